// Round 6
// baseline (279.571 us; speedup 1.0000x reference)
//
#include <hip/hip_runtime.h>

// All tensors FLOAT32 in/out. GEMMs: bf16 MFMA (err 0.031 < 0.108 thr).
// Interp: EXACT R0 brute-force scan/merge/selection (45.0us, green since R0;
// R1/R4 restructures regressed -> frozen). bf16 pre-conversion in prep +
// interp bf16-out (R5, green): every MFMA input bit-identical to baseline.
// This round (R6): GEMMs were latency-bound (~15-30us each vs ~4us floor) at
// 0.5-1 block/CU with 2 barriers/K-step. New GEMM structure: NO LDS staging,
// NO per-step barriers -- each lane loads its MFMA fragment DIRECTLY from
// global (16B per lane; same fragment the LDS path delivered -> bit-identical
// math, same acc order). Row-tile 64, grid 2x(M/64) = 1-2 blocks/CU, pure
// dataflow K-loop (compiler software-pipelines; ILP hides latency).
// BN stats: deterministic per-rowblock partials (NR=M/64), fixed-order
// reduce in gemm_b preamble. Zero atomics anywhere.

typedef __attribute__((ext_vector_type(8))) short bf16x8;
typedef __attribute__((ext_vector_type(4))) float f32x4;

__device__ __forceinline__ unsigned short f2bf(float f) {
    union { float f; unsigned u; } v; v.f = f;
    return (unsigned short)((v.u + 0x7fffu + ((v.u >> 16) & 1u)) >> 16); // RNE
}
__device__ __forceinline__ unsigned pack2(float a, float b) {
    return (unsigned)f2bf(a) | ((unsigned)f2bf(b) << 16);
}

// ---------- prep: xyz -> padded float4; bf16 pre-conversion ----------
__global__ __launch_bounds__(256)
void prep_kernel(const float* __restrict__ p1, const float* __restrict__ p2,
                 const float* __restrict__ p4,
                 const float* __restrict__ f0, const float* __restrict__ f1,
                 const float* __restrict__ w3a, const float* __restrict__ w4a,
                 const float* __restrict__ w3b, const float* __restrict__ w4b,
                 float4* __restrict__ x1, float4* __restrict__ x2,
                 float4* __restrict__ x4,
                 unsigned* __restrict__ f0b, unsigned* __restrict__ f1b,
                 unsigned* __restrict__ w3ab, unsigned* __restrict__ w4ab,
                 unsigned* __restrict__ w3bb, unsigned* __restrict__ w4bb) {
    int i = blockIdx.x * 256 + threadIdx.x;
    const int P1 = 16384, P2 = 8192, P4 = 4096;
    if (i < P1) {
        x1[i] = make_float4(p1[i*3], p1[i*3+1], p1[i*3+2], 0.f);
    } else if (i < P1 + P2) {
        int j = i - P1;
        x2[j] = make_float4(p2[j*3], p2[j*3+1], p2[j*3+2], 0.f);
    } else if (i < P1 + P2 + P4) {
        int j = i - P1 - P2;
        x4[j] = make_float4(p4[j*3], p4[j*3+1], p4[j*3+2], 0.f);
    }
    // grid-stride bf16 conversion (pairs of floats -> one u32 of 2 bf16)
    const int F0P = 1048576, F1P = 524288, WAP = 16384, WBP = 8192;
    const int TOT = F0P + F1P + WAP + WAP + WBP + WBP;   // 1,622,016 pairs
    const int NT = gridDim.x * 256;
    for (int p = i; p < TOT; p += NT) {
        const float* s; unsigned* d; int q = p;
        if (q < F0P)                { s = f0;  d = f0b;  }
        else if ((q -= F0P) < F1P)  { s = f1;  d = f1b;  }
        else if ((q -= F1P) < WAP)  { s = w3a; d = w3ab; }
        else if ((q -= WAP) < WAP)  { s = w4a; d = w4ab; }
        else if ((q -= WAP) < WBP)  { s = w3b; d = w3bb; }
        else       { q -= WBP;        s = w4b; d = w4bb; }
        float2 v = *(const float2*)(s + (size_t)q * 2);
        d[q] = pack2(v.x, v.y);
    }
}

// ---------- 3-NN interpolate (R0-exact scan/merge/selection; bf16 out) ----------
template<int CHUNK>
__global__ __launch_bounds__(256)
void nn_interp_kernel(const float4* __restrict__ tgt, int Nt,
                      const float4* __restrict__ src, int Ns,
                      const float* __restrict__ feats,
                      unsigned* __restrict__ out) {
    int tid = threadIdx.x;
    int pl = tid & 7, ch = tid >> 3;
    int b = blockIdx.y;
    int tbase = blockIdx.x * 8;
    float4 ta = tgt[b * Nt + tbase + pl];

    float a0=3.4e38f, a1=3.4e38f, a2=3.4e38f;
    int ia0=0, ia1=0, ia2=0;
    const float4* sp = src + b * Ns + ch * CHUNK;
    #pragma unroll 8
    for (int j = 0; j < CHUNK; ++j) {
        float4 s = sp[j];
        int idx = ch * CHUNK + j;
        float dx = ta.x - s.x, dy = ta.y - s.y, dz = ta.z - s.z;
        float d2 = __fadd_rn(__fadd_rn(__fmul_rn(dx,dx), __fmul_rn(dy,dy)),
                             __fmul_rn(dz,dz));
        bool c0 = d2 < a0, c1 = d2 < a1, c2 = d2 < a2;
        float na2 = fminf(a2, fmaxf(a1, d2));
        float na1 = __builtin_amdgcn_fmed3f(a0, a1, d2);
        float na0 = fminf(a0, d2);
        ia2 = c1 ? ia1 : (c2 ? idx : ia2);
        ia1 = c0 ? ia0 : (c1 ? idx : ia1);
        ia0 = c0 ? idx : ia0;
        a0 = na0; a1 = na1; a2 = na2;
    }

    __shared__ float sd[8][32][3];
    __shared__ int   si[8][32][3];
    __shared__ float pd[8][4][3];
    __shared__ int   pi[8][4][3];
    __shared__ float sw[8][3];
    __shared__ int   sg[8][3];
    sd[pl][ch][0]=a0; sd[pl][ch][1]=a1; sd[pl][ch][2]=a2;
    si[pl][ch][0]=ia0; si[pl][ch][1]=ia1; si[pl][ch][2]=ia2;
    __syncthreads();

    if (tid < 32) {
        int tt = tid >> 2, m = tid & 3;
        float m0=3.4e38f, m1=3.4e38f, m2=3.4e38f;
        int j0=0, j1=0, j2=0;
        #pragma unroll
        for (int cc = m * 8; cc < m * 8 + 8; ++cc) {
            #pragma unroll
            for (int k = 0; k < 3; ++k) {
                float d = sd[tt][cc][k]; int ix = si[tt][cc][k];
                bool c0 = d < m0, c1 = d < m1, c2 = d < m2;
                m2 = c1 ? m1 : (c2 ? d : m2);  j2 = c1 ? j1 : (c2 ? ix : j2);
                m1 = c0 ? m0 : (c1 ? d : m1);  j1 = c0 ? j0 : (c1 ? ix : j1);
                m0 = c0 ? d : m0;              j0 = c0 ? ix : j0;
            }
        }
        pd[tt][m][0]=m0; pd[tt][m][1]=m1; pd[tt][m][2]=m2;
        pi[tt][m][0]=j0; pi[tt][m][1]=j1; pi[tt][m][2]=j2;
    }
    __syncthreads();

    if (tid < 8) {
        float m0=3.4e38f, m1=3.4e38f, m2=3.4e38f;
        int j0=0, j1=0, j2=0;
        #pragma unroll
        for (int m = 0; m < 4; ++m) {
            #pragma unroll
            for (int k = 0; k < 3; ++k) {
                float d = pd[tid][m][k]; int ix = pi[tid][m][k];
                bool c0 = d < m0, c1 = d < m1, c2 = d < m2;
                m2 = c1 ? m1 : (c2 ? d : m2);  j2 = c1 ? j1 : (c2 ? ix : j2);
                m1 = c0 ? m0 : (c1 ? d : m1);  j1 = c0 ? j0 : (c1 ? ix : j1);
                m0 = c0 ? d : m0;              j0 = c0 ? ix : j0;
            }
        }
        float d0 = sqrtf(fmaxf(m0, 0.f));
        float d1 = sqrtf(fmaxf(m1, 0.f));
        float d2 = sqrtf(fmaxf(m2, 0.f));
        float w0 = 1.f / (d0 + 1e-8f);
        float w1 = 1.f / (d1 + 1e-8f);
        float w2 = 1.f / (d2 + 1e-8f);
        float wsum = w0 + w1 + w2;
        sw[tid][0] = w0 / wsum; sw[tid][1] = w1 / wsum; sw[tid][2] = w2 / wsum;
        sg[tid][0] = j0; sg[tid][1] = j1; sg[tid][2] = j2;
    }
    __syncthreads();

    for (int e = tid; e < 8 * 64; e += 256) {
        int tt = e >> 6, cp = (e & 63) * 2;
        int base = b * Ns * 128;
        float2 f0  = *(const float2*)&feats[base + sg[tt][0] * 128 + cp];
        float2 f1  = *(const float2*)&feats[base + sg[tt][1] * 128 + cp];
        float2 f2v = *(const float2*)&feats[base + sg[tt][2] * 128 + cp];
        float ox = sw[tt][0] * f0.x + sw[tt][1] * f1.x + sw[tt][2] * f2v.x;
        float oy = sw[tt][0] * f0.y + sw[tt][1] * f1.y + sw[tt][2] * f2v.y;
        out[(b * Nt + tbase + tt) * 64 + (cp >> 1)] = pack2(ox, oy);
    }
}

// ---------- GEMM A: barrier-free direct-fragment loads ----------
// H = [L|R] @ W^T. Block 256 = 4 waves; wave w owns 16 rows; 64 rows/block.
// Lane fragment == old LDS path fragment (row=lane&15, k=quad*8..+8) ->
// bit-identical MFMA inputs & acc order. LDS only for BN-stat reduce.
__global__ __launch_bounds__(256)
void gemm_a_kernel(const unsigned short* __restrict__ Lb,
                   const unsigned short* __restrict__ Rb,
                   const unsigned short* __restrict__ Wb,
                   float* __restrict__ H, float* __restrict__ stp) {
    __shared__ float ssum[16 * 64];
    __shared__ float ssq[16 * 64];
    int tid = threadIdx.x;
    int lane = tid & 63, w = tid >> 6;
    int m16 = lane & 15, quad = lane >> 4;
    int colBase = blockIdx.x * 64;
    int arow = blockIdx.y * 64 + w * 16 + m16;      // row this lane loads
    const unsigned short* lrow = Lb + (size_t)arow * 128;
    const unsigned short* rrow = Rb + (size_t)arow * 128;

    f32x4 acc[4] = {};
    #pragma unroll
    for (int k0 = 0; k0 < 256; k0 += 32) {
        const unsigned short* ap = (k0 < 128) ? (lrow + k0) : (rrow + k0 - 128);
        bf16x8 a = *(const bf16x8*)(ap + quad * 8);
        #pragma unroll
        for (int ct = 0; ct < 4; ++ct) {
            bf16x8 b = *(const bf16x8*)&Wb[(size_t)(colBase + ct * 16 + m16) * 256
                                           + k0 + quad * 8];
            acc[ct] = __builtin_amdgcn_mfma_f32_16x16x32_bf16(a, b, acc[ct], 0, 0, 0);
        }
    }

    // C write: out row = base + quad*4 + r, col = colBase + ct*16 + m16
    int orow = blockIdx.y * 64 + w * 16 + quad * 4;
    #pragma unroll
    for (int ct = 0; ct < 4; ++ct)
        #pragma unroll
        for (int r = 0; r < 4; ++r)
            H[(size_t)(orow + r) * 128 + colBase + ct * 16 + m16] = acc[ct][r];

    // BN-stat partials (deterministic): per-thread sums -> LDS -> fixed-order
    #pragma unroll
    for (int ct = 0; ct < 4; ++ct) {
        float s = 0.f, q = 0.f;
        #pragma unroll
        for (int r = 0; r < 4; ++r) { float v = acc[ct][r]; s += v; q += v * v; }
        ssum[(w * 4 + quad) * 64 + ct * 16 + m16] = s;
        ssq [(w * 4 + quad) * 64 + ct * 16 + m16] = q;
    }
    __syncthreads();
    if (tid < 64) {
        float s = 0.f, q = 0.f;
        #pragma unroll
        for (int i = 0; i < 16; ++i) { s += ssum[i * 64 + tid]; q += ssq[i * 64 + tid]; }
        stp[blockIdx.y * 256 + colBase + tid] = s;
        stp[blockIdx.y * 256 + 128 + colBase + tid] = q;
    }
}

// ---------- GEMM B: barrier-free tiles; BN finalize fused ----------
__global__ __launch_bounds__(256)
void gemm_b_kernel(const float* __restrict__ Hin, const float* __restrict__ stp,
                   int NR, const float* __restrict__ gam, const float* __restrict__ bet,
                   float invN, const unsigned short* __restrict__ Wb,
                   const float* __restrict__ bias, float* __restrict__ out) {
    __shared__ float ssc[128], ssf[128];
    int tid = threadIdx.x;
    if (tid < 128) {
        float s = 0.f, q = 0.f;
        for (int r = 0; r < NR; ++r) {          // fixed order -> deterministic
            s += stp[r * 256 + tid];
            q += stp[r * 256 + 128 + tid];
        }
        float mu = s * invN;
        float var = q * invN - mu * mu;
        float rstd = rsqrtf(fmaxf(var, 0.f) + 1e-5f);
        float sc = rstd * gam[tid];
        ssc[tid] = sc;
        ssf[tid] = bet[tid] - mu * sc;
    }
    __syncthreads();

    int lane = tid & 63, w = tid >> 6;
    int m16 = lane & 15, quad = lane >> 4;
    int colBase = blockIdx.x * 64;
    int arow = blockIdx.y * 64 + w * 16 + m16;
    const float* hrow = Hin + (size_t)arow * 128;

    f32x4 acc[4] = {};
    #pragma unroll
    for (int k0 = 0; k0 < 128; k0 += 32) {
        int c = k0 + quad * 8;
        float4 x = *(const float4*)(hrow + c);
        float4 y = *(const float4*)(hrow + c + 4);
        float h0 = fmaxf(x.x * ssc[c+0] + ssf[c+0], 0.f);
        float h1 = fmaxf(x.y * ssc[c+1] + ssf[c+1], 0.f);
        float h2 = fmaxf(x.z * ssc[c+2] + ssf[c+2], 0.f);
        float h3 = fmaxf(x.w * ssc[c+3] + ssf[c+3], 0.f);
        float h4 = fmaxf(y.x * ssc[c+4] + ssf[c+4], 0.f);
        float h5 = fmaxf(y.y * ssc[c+5] + ssf[c+5], 0.f);
        float h6 = fmaxf(y.z * ssc[c+6] + ssf[c+6], 0.f);
        float h7 = fmaxf(y.w * ssc[c+7] + ssf[c+7], 0.f);
        union { unsigned u[4]; bf16x8 v; } av;
        av.u[0] = pack2(h0, h1); av.u[1] = pack2(h2, h3);
        av.u[2] = pack2(h4, h5); av.u[3] = pack2(h6, h7);
        bf16x8 a = av.v;
        #pragma unroll
        for (int ct = 0; ct < 4; ++ct) {
            bf16x8 b = *(const bf16x8*)&Wb[(size_t)(colBase + ct * 16 + m16) * 128
                                           + k0 + quad * 8];
            acc[ct] = __builtin_amdgcn_mfma_f32_16x16x32_bf16(a, b, acc[ct], 0, 0, 0);
        }
    }

    int orow = blockIdx.y * 64 + w * 16 + quad * 4;
    #pragma unroll
    for (int ct = 0; ct < 4; ++ct) {
        float bv = bias[colBase + ct * 16 + m16];
        #pragma unroll
        for (int r = 0; r < 4; ++r)
            out[(size_t)(orow + r) * 128 + colBase + ct * 16 + m16] = acc[ct][r] + bv;
    }
}

extern "C" void kernel_launch(void* const* d_in, const int* in_sizes, int n_in,
                              void* d_out, int out_size, void* d_ws, size_t ws_size,
                              hipStream_t stream) {
    const float* pts_r1 = (const float*)d_in[0];   // (2,8192,3)
    const float* pts_r2 = (const float*)d_in[1];   // (2,4096,3)
    const float* pts_r4 = (const float*)d_in[2];   // (2,2048,3)
    const float* feat0  = (const float*)d_in[3];   // (16384,128)
    const float* feat1  = (const float*)d_in[4];   // (8192,128)
    const float* feat2  = (const float*)d_in[5];   // (4096,128)
    const float* w3a = (const float*)d_in[6];      // (128,256)
    const float* g3  = (const float*)d_in[7];
    const float* b3  = (const float*)d_in[8];
    const float* w3b = (const float*)d_in[9];      // (128,128)
    const float* bb3 = (const float*)d_in[10];
    const float* w4a = (const float*)d_in[11];     // (128,256)
    const float* g4  = (const float*)d_in[12];
    const float* b4  = (const float*)d_in[13];
    const float* w4b = (const float*)d_in[14];     // (128,128)
    const float* bb4 = (const float*)d_in[15];

    float* wsf = (float*)d_ws;
    // ---- lifetimes (float offsets) ----
    float4* xyz1 = (float4*)(wsf + 0);          // [0, 65536)
    float4* xyz2 = (float4*)(wsf + 65536);      // [65536, 98304)
    float4* xyz4 = (float4*)(wsf + 98304);      // [98304, 114688)
    unsigned* f2ib = (unsigned*)(wsf + 114688); // bf16 8192x128 [114688, 638976)
    float* H1  = wsf + 638976;                  // [638976, 1687552)
    float* n3  = wsf + 1687552;                 // [1687552, 2736128)
    unsigned* n3ib = (unsigned*)(wsf + 114688); // bf16 16384x128 [114688,1163264)
                                                //   over f2ib+H1 (both dead)
    float* H2  = wsf + 2736128;                 // [2736128, 4833280)
    unsigned* f1b  = (unsigned*)(wsf + 2736128);// bf16 feat1 [2736128, 3260416)
                                                //   in H2 head (dead before H2)
    unsigned* w3ab = (unsigned*)(wsf + 4833280);// [4833280, 4849664)
    unsigned* w4ab = (unsigned*)(wsf + 4849664);// [4849664, 4866048)
    unsigned* w3bb = (unsigned*)(wsf + 4866048);// [4866048, 4874240)
    unsigned* w4bb = (unsigned*)(wsf + 4874240);// [4874240, 4882432)
    float* st1p = wsf + 4882432;                // 128*256 [4882432, 4915200)
    float* st2p = wsf + 4915200;                // 256*256 [4915200, 4980736)
    unsigned* f0b = (unsigned*)d_out;           // bf16 feat0 in d_out head
                                                //   (dead once gemm_b_f4 writes)

    // 1. prep: pad xyz + one-shot bf16 conversion of L-operands and weights
    prep_kernel<<<512, 256, 0, stream>>>(pts_r1, pts_r2, pts_r4,
                                         feat0, feat1, w3a, w4a, w3b, w4b,
                                         xyz1, xyz2, xyz4,
                                         f0b, f1b, w3ab, w4ab, w3bb, w4bb);
    // 2. interp #1: feat2 (fp32) on pts_r4 grid -> pts_r2 targets, bf16 out
    nn_interp_kernel<64><<<dim3(512, 2), 256, 0, stream>>>(xyz2, 4096, xyz4, 2048,
                                                           feat2, f2ib);
    // 3. fnode 3 (M=8192): grid 2 x M/64
    gemm_a_kernel<<<dim3(2, 128), 256, 0, stream>>>(
        (const unsigned short*)f1b, (const unsigned short*)f2ib,
        (const unsigned short*)w3ab, H1, st1p);
    gemm_b_kernel<<<dim3(2, 128), 256, 0, stream>>>(
        H1, st1p, 128, g3, b3, 1.f / 8192.f,
        (const unsigned short*)w3bb, bb3, n3);
    // 4. interp #2: n3 (fp32) on pts_r2 grid -> pts_r1 targets, bf16 out
    nn_interp_kernel<128><<<dim3(1024, 2), 256, 0, stream>>>(xyz1, 8192, xyz2, 4096,
                                                             n3, n3ib);
    // 5. fnode 4 (M=16384): grid 2 x M/64
    gemm_a_kernel<<<dim3(2, 256), 256, 0, stream>>>(
        (const unsigned short*)f0b, (const unsigned short*)n3ib,
        (const unsigned short*)w4ab, H2, st2p);
    gemm_b_kernel<<<dim3(2, 256), 256, 0, stream>>>(
        H2, st2p, 256, g4, b4, 1.f / 16384.f,
        (const unsigned short*)w4bb, bb4, (float*)d_out);
}

// Round 7
// 197.077 us; speedup vs baseline: 1.4186x; 1.4186x over previous
//
#include <hip/hip_runtime.h>

// All tensors FLOAT32 in/out. GEMMs: bf16 MFMA (err 0.031 < 0.108 thr).
// Interp: EXACT R0 brute-force scan/merge/selection (45.0us, frozen).
// bf16 pre-conversion in prep + interp bf16-out (R5, green).
// R6 lesson (counters): barrier-free fragment-direct GEMM works (gemm_a ~10us)
// but fusing the BN-stat reduce into gemm_b's preamble serialized it: 128 thr
// x NR runtime-trip dependent loads = ~25-55us exposed latency x ~2 serial
// blocks/CU -> 74us, MfmaUtil 0.26%. This round: BN finalize hoisted to a
// tiny dedicated kernel (1 block x 1024 thr, 4-chunk parallel reduce, 16
// waves hide latency); gemm_b preamble = 2 coalesced loads. GEMM math
// bit-identical; BN stat sum order = fixed deterministic tree (negligible
// fp32 perturbation, well under threshold). Zero atomics anywhere.

typedef __attribute__((ext_vector_type(8))) short bf16x8;
typedef __attribute__((ext_vector_type(4))) float f32x4;

__device__ __forceinline__ unsigned short f2bf(float f) {
    union { float f; unsigned u; } v; v.f = f;
    return (unsigned short)((v.u + 0x7fffu + ((v.u >> 16) & 1u)) >> 16); // RNE
}
__device__ __forceinline__ unsigned pack2(float a, float b) {
    return (unsigned)f2bf(a) | ((unsigned)f2bf(b) << 16);
}

// ---------- prep: xyz -> padded float4; bf16 pre-conversion ----------
__global__ __launch_bounds__(256)
void prep_kernel(const float* __restrict__ p1, const float* __restrict__ p2,
                 const float* __restrict__ p4,
                 const float* __restrict__ f0, const float* __restrict__ f1,
                 const float* __restrict__ w3a, const float* __restrict__ w4a,
                 const float* __restrict__ w3b, const float* __restrict__ w4b,
                 float4* __restrict__ x1, float4* __restrict__ x2,
                 float4* __restrict__ x4,
                 unsigned* __restrict__ f0b, unsigned* __restrict__ f1b,
                 unsigned* __restrict__ w3ab, unsigned* __restrict__ w4ab,
                 unsigned* __restrict__ w3bb, unsigned* __restrict__ w4bb) {
    int i = blockIdx.x * 256 + threadIdx.x;
    const int P1 = 16384, P2 = 8192, P4 = 4096;
    if (i < P1) {
        x1[i] = make_float4(p1[i*3], p1[i*3+1], p1[i*3+2], 0.f);
    } else if (i < P1 + P2) {
        int j = i - P1;
        x2[j] = make_float4(p2[j*3], p2[j*3+1], p2[j*3+2], 0.f);
    } else if (i < P1 + P2 + P4) {
        int j = i - P1 - P2;
        x4[j] = make_float4(p4[j*3], p4[j*3+1], p4[j*3+2], 0.f);
    }
    // grid-stride bf16 conversion (pairs of floats -> one u32 of 2 bf16)
    const int F0P = 1048576, F1P = 524288, WAP = 16384, WBP = 8192;
    const int TOT = F0P + F1P + WAP + WAP + WBP + WBP;   // 1,622,016 pairs
    const int NT = gridDim.x * 256;
    for (int p = i; p < TOT; p += NT) {
        const float* s; unsigned* d; int q = p;
        if (q < F0P)                { s = f0;  d = f0b;  }
        else if ((q -= F0P) < F1P)  { s = f1;  d = f1b;  }
        else if ((q -= F1P) < WAP)  { s = w3a; d = w3ab; }
        else if ((q -= WAP) < WAP)  { s = w4a; d = w4ab; }
        else if ((q -= WAP) < WBP)  { s = w3b; d = w3bb; }
        else       { q -= WBP;        s = w4b; d = w4bb; }
        float2 v = *(const float2*)(s + (size_t)q * 2);
        d[q] = pack2(v.x, v.y);
    }
}

// ---------- 3-NN interpolate (R0-exact scan/merge/selection; bf16 out) ----------
template<int CHUNK>
__global__ __launch_bounds__(256)
void nn_interp_kernel(const float4* __restrict__ tgt, int Nt,
                      const float4* __restrict__ src, int Ns,
                      const float* __restrict__ feats,
                      unsigned* __restrict__ out) {
    int tid = threadIdx.x;
    int pl = tid & 7, ch = tid >> 3;
    int b = blockIdx.y;
    int tbase = blockIdx.x * 8;
    float4 ta = tgt[b * Nt + tbase + pl];

    float a0=3.4e38f, a1=3.4e38f, a2=3.4e38f;
    int ia0=0, ia1=0, ia2=0;
    const float4* sp = src + b * Ns + ch * CHUNK;
    #pragma unroll 8
    for (int j = 0; j < CHUNK; ++j) {
        float4 s = sp[j];
        int idx = ch * CHUNK + j;
        float dx = ta.x - s.x, dy = ta.y - s.y, dz = ta.z - s.z;
        float d2 = __fadd_rn(__fadd_rn(__fmul_rn(dx,dx), __fmul_rn(dy,dy)),
                             __fmul_rn(dz,dz));
        bool c0 = d2 < a0, c1 = d2 < a1, c2 = d2 < a2;
        float na2 = fminf(a2, fmaxf(a1, d2));
        float na1 = __builtin_amdgcn_fmed3f(a0, a1, d2);
        float na0 = fminf(a0, d2);
        ia2 = c1 ? ia1 : (c2 ? idx : ia2);
        ia1 = c0 ? ia0 : (c1 ? idx : ia1);
        ia0 = c0 ? idx : ia0;
        a0 = na0; a1 = na1; a2 = na2;
    }

    __shared__ float sd[8][32][3];
    __shared__ int   si[8][32][3];
    __shared__ float pd[8][4][3];
    __shared__ int   pi[8][4][3];
    __shared__ float sw[8][3];
    __shared__ int   sg[8][3];
    sd[pl][ch][0]=a0; sd[pl][ch][1]=a1; sd[pl][ch][2]=a2;
    si[pl][ch][0]=ia0; si[pl][ch][1]=ia1; si[pl][ch][2]=ia2;
    __syncthreads();

    if (tid < 32) {
        int tt = tid >> 2, m = tid & 3;
        float m0=3.4e38f, m1=3.4e38f, m2=3.4e38f;
        int j0=0, j1=0, j2=0;
        #pragma unroll
        for (int cc = m * 8; cc < m * 8 + 8; ++cc) {
            #pragma unroll
            for (int k = 0; k < 3; ++k) {
                float d = sd[tt][cc][k]; int ix = si[tt][cc][k];
                bool c0 = d < m0, c1 = d < m1, c2 = d < m2;
                m2 = c1 ? m1 : (c2 ? d : m2);  j2 = c1 ? j1 : (c2 ? ix : j2);
                m1 = c0 ? m0 : (c1 ? d : m1);  j1 = c0 ? j0 : (c1 ? ix : j1);
                m0 = c0 ? d : m0;              j0 = c0 ? ix : j0;
            }
        }
        pd[tt][m][0]=m0; pd[tt][m][1]=m1; pd[tt][m][2]=m2;
        pi[tt][m][0]=j0; pi[tt][m][1]=j1; pi[tt][m][2]=j2;
    }
    __syncthreads();

    if (tid < 8) {
        float m0=3.4e38f, m1=3.4e38f, m2=3.4e38f;
        int j0=0, j1=0, j2=0;
        #pragma unroll
        for (int m = 0; m < 4; ++m) {
            #pragma unroll
            for (int k = 0; k < 3; ++k) {
                float d = pd[tid][m][k]; int ix = pi[tid][m][k];
                bool c0 = d < m0, c1 = d < m1, c2 = d < m2;
                m2 = c1 ? m1 : (c2 ? d : m2);  j2 = c1 ? j1 : (c2 ? ix : j2);
                m1 = c0 ? m0 : (c1 ? d : m1);  j1 = c0 ? j0 : (c1 ? ix : j1);
                m0 = c0 ? d : m0;              j0 = c0 ? ix : j0;
            }
        }
        float d0 = sqrtf(fmaxf(m0, 0.f));
        float d1 = sqrtf(fmaxf(m1, 0.f));
        float d2 = sqrtf(fmaxf(m2, 0.f));
        float w0 = 1.f / (d0 + 1e-8f);
        float w1 = 1.f / (d1 + 1e-8f);
        float w2 = 1.f / (d2 + 1e-8f);
        float wsum = w0 + w1 + w2;
        sw[tid][0] = w0 / wsum; sw[tid][1] = w1 / wsum; sw[tid][2] = w2 / wsum;
        sg[tid][0] = j0; sg[tid][1] = j1; sg[tid][2] = j2;
    }
    __syncthreads();

    for (int e = tid; e < 8 * 64; e += 256) {
        int tt = e >> 6, cp = (e & 63) * 2;
        int base = b * Ns * 128;
        float2 f0  = *(const float2*)&feats[base + sg[tt][0] * 128 + cp];
        float2 f1  = *(const float2*)&feats[base + sg[tt][1] * 128 + cp];
        float2 f2v = *(const float2*)&feats[base + sg[tt][2] * 128 + cp];
        float ox = sw[tt][0] * f0.x + sw[tt][1] * f1.x + sw[tt][2] * f2v.x;
        float oy = sw[tt][0] * f0.y + sw[tt][1] * f1.y + sw[tt][2] * f2v.y;
        out[(b * Nt + tbase + tt) * 64 + (cp >> 1)] = pack2(ox, oy);
    }
}

// ---------- GEMM A: barrier-free direct-fragment loads (R6-proven fast) ----------
__global__ __launch_bounds__(256)
void gemm_a_kernel(const unsigned short* __restrict__ Lb,
                   const unsigned short* __restrict__ Rb,
                   const unsigned short* __restrict__ Wb,
                   float* __restrict__ H, float* __restrict__ stp) {
    __shared__ float ssum[16 * 64];
    __shared__ float ssq[16 * 64];
    int tid = threadIdx.x;
    int lane = tid & 63, w = tid >> 6;
    int m16 = lane & 15, quad = lane >> 4;
    int colBase = blockIdx.x * 64;
    int arow = blockIdx.y * 64 + w * 16 + m16;      // row this lane loads
    const unsigned short* lrow = Lb + (size_t)arow * 128;
    const unsigned short* rrow = Rb + (size_t)arow * 128;

    f32x4 acc[4] = {};
    #pragma unroll
    for (int k0 = 0; k0 < 256; k0 += 32) {
        const unsigned short* ap = (k0 < 128) ? (lrow + k0) : (rrow + k0 - 128);
        bf16x8 a = *(const bf16x8*)(ap + quad * 8);
        #pragma unroll
        for (int ct = 0; ct < 4; ++ct) {
            bf16x8 b = *(const bf16x8*)&Wb[(size_t)(colBase + ct * 16 + m16) * 256
                                           + k0 + quad * 8];
            acc[ct] = __builtin_amdgcn_mfma_f32_16x16x32_bf16(a, b, acc[ct], 0, 0, 0);
        }
    }

    int orow = blockIdx.y * 64 + w * 16 + quad * 4;
    #pragma unroll
    for (int ct = 0; ct < 4; ++ct)
        #pragma unroll
        for (int r = 0; r < 4; ++r)
            H[(size_t)(orow + r) * 128 + colBase + ct * 16 + m16] = acc[ct][r];

    // BN-stat partials (deterministic): per-thread sums -> LDS -> fixed-order
    #pragma unroll
    for (int ct = 0; ct < 4; ++ct) {
        float s = 0.f, q = 0.f;
        #pragma unroll
        for (int r = 0; r < 4; ++r) { float v = acc[ct][r]; s += v; q += v * v; }
        ssum[(w * 4 + quad) * 64 + ct * 16 + m16] = s;
        ssq [(w * 4 + quad) * 64 + ct * 16 + m16] = q;
    }
    __syncthreads();
    if (tid < 64) {
        float s = 0.f, q = 0.f;
        #pragma unroll
        for (int i = 0; i < 16; ++i) { s += ssum[i * 64 + tid]; q += ssq[i * 64 + tid]; }
        stp[blockIdx.y * 256 + colBase + tid] = s;
        stp[blockIdx.y * 256 + 128 + colBase + tid] = q;
    }
}

// ---------- BN finalize: parallel reduce of rowblock partials ----------
// 1 block x 1024 thr: col = tid&255 (128 sums | 128 sumsqs), 4 chunks over NR.
// Fixed tree order -> deterministic across launch mechanisms.
__global__ __launch_bounds__(1024)
void bn_finalize_kernel(const float* __restrict__ stp, int NR, float invN,
                        const float* __restrict__ gam, const float* __restrict__ bet,
                        float* __restrict__ scg, float* __restrict__ sfg) {
    __shared__ float part[4][256];
    int tid = threadIdx.x;
    int col = tid & 255, chunk = tid >> 8;
    int cn = NR >> 2;
    float s = 0.f;
    #pragma unroll 8
    for (int r = chunk * cn; r < (chunk + 1) * cn; ++r)
        s += stp[r * 256 + col];
    part[chunk][col] = s;
    __syncthreads();
    if (tid < 256) {
        float tot = ((part[0][tid] + part[1][tid]) + part[2][tid]) + part[3][tid];
        part[0][tid] = tot;
    }
    __syncthreads();
    if (tid < 128) {
        float mu = part[0][tid] * invN;
        float var = part[0][128 + tid] * invN - mu * mu;
        float rstd = rsqrtf(fmaxf(var, 0.f) + 1e-5f);
        float sc = rstd * gam[tid];
        scg[tid] = sc;
        sfg[tid] = bet[tid] - mu * sc;
    }
}

// ---------- GEMM B: barrier-free tiles; BN apply fused (scale precomputed) ----------
__global__ __launch_bounds__(256)
void gemm_b_kernel(const float* __restrict__ Hin,
                   const float* __restrict__ scg, const float* __restrict__ sfg,
                   const unsigned short* __restrict__ Wb,
                   const float* __restrict__ bias, float* __restrict__ out) {
    __shared__ float ssc[128], ssf[128];
    int tid = threadIdx.x;
    if (tid < 128) { ssc[tid] = scg[tid]; ssf[tid] = sfg[tid]; }
    __syncthreads();

    int lane = tid & 63, w = tid >> 6;
    int m16 = lane & 15, quad = lane >> 4;
    int colBase = blockIdx.x * 64;
    int arow = blockIdx.y * 64 + w * 16 + m16;
    const float* hrow = Hin + (size_t)arow * 128;

    f32x4 acc[4] = {};
    #pragma unroll
    for (int k0 = 0; k0 < 128; k0 += 32) {
        int c = k0 + quad * 8;
        float4 x = *(const float4*)(hrow + c);
        float4 y = *(const float4*)(hrow + c + 4);
        float h0 = fmaxf(x.x * ssc[c+0] + ssf[c+0], 0.f);
        float h1 = fmaxf(x.y * ssc[c+1] + ssf[c+1], 0.f);
        float h2 = fmaxf(x.z * ssc[c+2] + ssf[c+2], 0.f);
        float h3 = fmaxf(x.w * ssc[c+3] + ssf[c+3], 0.f);
        float h4 = fmaxf(y.x * ssc[c+4] + ssf[c+4], 0.f);
        float h5 = fmaxf(y.y * ssc[c+5] + ssf[c+5], 0.f);
        float h6 = fmaxf(y.z * ssc[c+6] + ssf[c+6], 0.f);
        float h7 = fmaxf(y.w * ssc[c+7] + ssf[c+7], 0.f);
        union { unsigned u[4]; bf16x8 v; } av;
        av.u[0] = pack2(h0, h1); av.u[1] = pack2(h2, h3);
        av.u[2] = pack2(h4, h5); av.u[3] = pack2(h6, h7);
        bf16x8 a = av.v;
        #pragma unroll
        for (int ct = 0; ct < 4; ++ct) {
            bf16x8 b = *(const bf16x8*)&Wb[(size_t)(colBase + ct * 16 + m16) * 128
                                           + k0 + quad * 8];
            acc[ct] = __builtin_amdgcn_mfma_f32_16x16x32_bf16(a, b, acc[ct], 0, 0, 0);
        }
    }

    int orow = blockIdx.y * 64 + w * 16 + quad * 4;
    #pragma unroll
    for (int ct = 0; ct < 4; ++ct) {
        float bv = bias[colBase + ct * 16 + m16];
        #pragma unroll
        for (int r = 0; r < 4; ++r)
            out[(size_t)(orow + r) * 128 + colBase + ct * 16 + m16] = acc[ct][r] + bv;
    }
}

extern "C" void kernel_launch(void* const* d_in, const int* in_sizes, int n_in,
                              void* d_out, int out_size, void* d_ws, size_t ws_size,
                              hipStream_t stream) {
    const float* pts_r1 = (const float*)d_in[0];   // (2,8192,3)
    const float* pts_r2 = (const float*)d_in[1];   // (2,4096,3)
    const float* pts_r4 = (const float*)d_in[2];   // (2,2048,3)
    const float* feat0  = (const float*)d_in[3];   // (16384,128)
    const float* feat1  = (const float*)d_in[4];   // (8192,128)
    const float* feat2  = (const float*)d_in[5];   // (4096,128)
    const float* w3a = (const float*)d_in[6];      // (128,256)
    const float* g3  = (const float*)d_in[7];
    const float* b3  = (const float*)d_in[8];
    const float* w3b = (const float*)d_in[9];      // (128,128)
    const float* bb3 = (const float*)d_in[10];
    const float* w4a = (const float*)d_in[11];     // (128,256)
    const float* g4  = (const float*)d_in[12];
    const float* b4  = (const float*)d_in[13];
    const float* w4b = (const float*)d_in[14];     // (128,128)
    const float* bb4 = (const float*)d_in[15];

    float* wsf = (float*)d_ws;
    // ---- lifetimes (float offsets) ----
    float4* xyz1 = (float4*)(wsf + 0);          // [0, 65536)
    float4* xyz2 = (float4*)(wsf + 65536);      // [65536, 98304)
    float4* xyz4 = (float4*)(wsf + 98304);      // [98304, 114688)
    unsigned* f2ib = (unsigned*)(wsf + 114688); // bf16 8192x128 [114688, 638976)
    float* H1  = wsf + 638976;                  // [638976, 1687552)
    float* n3  = wsf + 1687552;                 // [1687552, 2736128)
    unsigned* n3ib = (unsigned*)(wsf + 114688); // bf16 16384x128 [114688,1163264)
                                                //   over f2ib+H1 (both dead)
    float* H2  = wsf + 2736128;                 // [2736128, 4833280)
    unsigned* f1b  = (unsigned*)(wsf + 2736128);// bf16 feat1 [2736128, 3260416)
                                                //   in H2 head (dead before H2)
    unsigned* w3ab = (unsigned*)(wsf + 4833280);// [4833280, 4849664)
    unsigned* w4ab = (unsigned*)(wsf + 4849664);// [4849664, 4866048)
    unsigned* w3bb = (unsigned*)(wsf + 4866048);// [4866048, 4874240)
    unsigned* w4bb = (unsigned*)(wsf + 4874240);// [4874240, 4882432)
    float* st1p = wsf + 4882432;                // 128*256 [4882432, 4915200)
    float* st2p = wsf + 4915200;                // 256*256 [4915200, 4980736)
    float* sc3  = wsf + 4980736;                // [4980736, 4980864)
    float* sf3  = wsf + 4980864;                // [4980864, 4980992)
    float* sc4  = wsf + 4980992;                // [4980992, 4981120)
    float* sf4  = wsf + 4981120;                // [4981120, 4981248)
    unsigned* f0b = (unsigned*)d_out;           // bf16 feat0 in d_out head
                                                //   (dead once gemm_b_f4 writes)

    // 1. prep: pad xyz + one-shot bf16 conversion of L-operands and weights
    prep_kernel<<<512, 256, 0, stream>>>(pts_r1, pts_r2, pts_r4,
                                         feat0, feat1, w3a, w4a, w3b, w4b,
                                         xyz1, xyz2, xyz4,
                                         f0b, f1b, w3ab, w4ab, w3bb, w4bb);
    // 2. interp #1: feat2 (fp32) on pts_r4 grid -> pts_r2 targets, bf16 out
    nn_interp_kernel<64><<<dim3(512, 2), 256, 0, stream>>>(xyz2, 4096, xyz4, 2048,
                                                           feat2, f2ib);
    // 3. fnode 3 (M=8192)
    gemm_a_kernel<<<dim3(2, 128), 256, 0, stream>>>(
        (const unsigned short*)f1b, (const unsigned short*)f2ib,
        (const unsigned short*)w3ab, H1, st1p);
    bn_finalize_kernel<<<1, 1024, 0, stream>>>(st1p, 128, 1.f / 8192.f,
                                               g3, b3, sc3, sf3);
    gemm_b_kernel<<<dim3(2, 128), 256, 0, stream>>>(
        H1, sc3, sf3, (const unsigned short*)w3bb, bb3, n3);
    // 4. interp #2: n3 (fp32) on pts_r2 grid -> pts_r1 targets, bf16 out
    nn_interp_kernel<128><<<dim3(1024, 2), 256, 0, stream>>>(xyz1, 8192, xyz2, 4096,
                                                             n3, n3ib);
    // 5. fnode 4 (M=16384)
    gemm_a_kernel<<<dim3(2, 256), 256, 0, stream>>>(
        (const unsigned short*)f0b, (const unsigned short*)n3ib,
        (const unsigned short*)w4ab, H2, st2p);
    bn_finalize_kernel<<<1, 1024, 0, stream>>>(st2p, 256, 1.f / 16384.f,
                                               g4, b4, sc4, sf4);
    gemm_b_kernel<<<dim3(2, 256), 256, 0, stream>>>(
        H2, sc4, sf4, (const unsigned short*)w4bb, bb4, (float*)d_out);
}